// Round 12
// baseline (411.063 us; speedup 1.0000x reference)
//
#include <hip/hip_runtime.h>
#include <math.h>

#define BATCH 4096
#define T 128
#define HOR 24
#define HPS 17                     // hp row stride in uint words

#define LOG2E 1.44269504088896f
#define C2    2.88539008177793f   // 2*log2(e)

typedef _Float16 half2_t __attribute__((ext_vector_type(2)));
typedef float f2  __attribute__((ext_vector_type(2)));
typedef float f4v __attribute__((ext_vector_type(4)));

__device__ __forceinline__ float fexp2(float x){ return __builtin_amdgcn_exp2f(x); }
__device__ __forceinline__ float frcp(float x){ return __builtin_amdgcn_rcpf(x); }
__device__ __forceinline__ float fsig(float x){ return frcp(1.0f + fexp2(-LOG2E*x)); }
__device__ __forceinline__ float ftanh(float x){ return fmaf(-2.0f, frcp(1.0f + fexp2(C2*x)), 1.0f); }
__device__ __forceinline__ half2_t bch(unsigned u){ return __builtin_bit_cast(half2_t,u); }
__device__ __forceinline__ unsigned pk2(float a,float b){ return __builtin_bit_cast(unsigned, __builtin_amdgcn_cvt_pkrtz(a,b)); }
__device__ __forceinline__ float fdot2f(half2_t a, half2_t b, float c){
#if __has_builtin(__builtin_amdgcn_fdot2)
  return __builtin_amdgcn_fdot2(a,b,c,false);
#else
  return fmaf((float)a.x,(float)b.x, fmaf((float)a.y,(float)b.y,c));
#endif
}
__device__ __forceinline__ f2 pkfma(f2 a, f2 b, f2 c){ return __builtin_elementwise_fma(a,b,c); }

// ---- DPP wave64 reduction (R11-verified): VALU-rate, no LDS pipe ----
template <int CTRL, int RMASK>
__device__ __forceinline__ float dpp_add(float v) {
  int s = __builtin_amdgcn_update_dpp(0, __builtin_bit_cast(int, v), CTRL, RMASK, 0xf, true);
  return v + __builtin_bit_cast(float, s);
}
__device__ __forceinline__ float wavesum_dpp(float v) {
  v = dpp_add<0x111, 0xf>(v);   // row_shr:1
  v = dpp_add<0x112, 0xf>(v);   // row_shr:2
  v = dpp_add<0x114, 0xf>(v);   // row_shr:4
  v = dpp_add<0x118, 0xf>(v);   // row_shr:8
  v = dpp_add<0x142, 0xa>(v);   // row_bcast:15 -> rows 1,3
  v = dpp_add<0x143, 0xc>(v);   // row_bcast:31 -> rows 2,3
  return v;                     // total in lane 63
}
__device__ __forceinline__ float rdl63(float v){
  return __builtin_bit_cast(float, __builtin_amdgcn_readlane(__builtin_bit_cast(int, v), 63));
}

__device__ __forceinline__ void gru_mv(const _Float16* hrow,
    const unsigned* wr_r, const unsigned* wr_z, const unsigned* wr_n,
    float& ar0, float& ar1, float& az0, float& az1, float& an0, float& an1)
{
  const uint4* hq = (const uint4*)hrow;      // broadcast reads (uniform addr)
  #pragma unroll
  for (int q = 0; q < 8; ++q) {
    uint4 hv = hq[q];
    ar0 = fdot2f(bch(hv.x), bch(wr_r[4*q+0]), ar0);
    az0 = fdot2f(bch(hv.x), bch(wr_z[4*q+0]), az0);
    an0 = fdot2f(bch(hv.x), bch(wr_n[4*q+0]), an0);
    ar1 = fdot2f(bch(hv.y), bch(wr_r[4*q+1]), ar1);
    az1 = fdot2f(bch(hv.y), bch(wr_z[4*q+1]), az1);
    an1 = fdot2f(bch(hv.y), bch(wr_n[4*q+1]), an1);
    ar0 = fdot2f(bch(hv.z), bch(wr_r[4*q+2]), ar0);
    az0 = fdot2f(bch(hv.z), bch(wr_z[4*q+2]), az0);
    an0 = fdot2f(bch(hv.z), bch(wr_n[4*q+2]), an0);
    ar1 = fdot2f(bch(hv.w), bch(wr_r[4*q+3]), ar1);
    az1 = fdot2f(bch(hv.w), bch(wr_z[4*q+3]), az1);
    an1 = fdot2f(bch(hv.w), bch(wr_n[4*q+3]), an1);
  }
}

__device__ __forceinline__ float proj_dot(const _Float16* base, const unsigned* udr)
{
  float acc = 0.f;
  const uint4* hb = (const uint4*)base;
  #pragma unroll
  for (int q = 0; q < 4; ++q) {
    uint4 hv = hb[q];
    acc = fdot2f(bch(hv.x), bch(udr[4*q+0]), acc);
    acc = fdot2f(bch(hv.y), bch(udr[4*q+1]), acc);
    acc = fdot2f(bch(hv.z), bch(udr[4*q+2]), acc);
    acc = fdot2f(bch(hv.w), bch(udr[4*q+3]), acc);
  }
  return acc;
}

// blockDim=128 = TWO independent waves, ONE batch element per wave.
// Rationale (R12): every 64-thread-block config measured ~7 waves/CU
// regardless of LDS headroom (R6/R7/R8), while a 256-thread config (R2)
// reached ~11 — the HW caps ~8 workgroups/CU. So buy waves via waves-per-
// workgroup: 8 blocks x 2 waves = 16 waves/CU = 4/SIMD (VGPR ~120 <= 128).
// Waves share nothing: private 10240-B LDS slices, ZERO barriers.
// __launch_bounds__(128,2): 256-reg budget. DO NOT raise (R5: spill, 80x FETCH).
__global__ __launch_bounds__(128, 2)
void darnn_kernel(const float* __restrict__ x,
                  const float* __restrict__ W_ih_e, const float* __restrict__ W_hh_e,
                  const float* __restrict__ b_ih_e, const float* __restrict__ b_hh_e,
                  const float* __restrict__ W_init, const float* __restrict__ b_init,
                  const float* __restrict__ W_ih_d, const float* __restrict__ W_hh_d,
                  const float* __restrict__ b_ih_d, const float* __restrict__ b_hh_d,
                  const float* __restrict__ W_d, const float* __restrict__ U_d,
                  const float* __restrict__ v_d, const float* __restrict__ W_out,
                  const float* __restrict__ b_out, const float* __restrict__ y0,
                  float* __restrict__ out)
{
  const int tid = threadIdx.x;
  const int wid = tid >> 6;            // wave 0/1 within block
  const int l   = tid & 63;            // lane
  const int b   = 2*blockIdx.x + wid;  // one element per wave
  const int a    = l & 31;
  const int half = l >> 5;

  // Per-wave LDS slice (10240 B each; block total 20480 B -> 8 blocks/CU):
  //  [0,8704)      unsigned hp[128][17]: cols 0..15 fp16-pair Hp (pre-scaled
  //                C2, pairs (a,a+1)); col 16 = hw[t] fp32 bits
  //  [8704,9856)   fp16 ring 8 rows x 72 (decoder: row 0 = d)
  //  [9856,10112)  x fp16[128]  (reused after encoder: h_T f32[64])
  //  [10112,10240) dp f32[32]
  __shared__ __align__(16) unsigned char smem[20480];
  unsigned char* wb = smem + wid*10240;
  unsigned* sh_hp   = (unsigned*)wb;
  _Float16* sh_ring = (_Float16*)(wb + 8704);
  _Float16* sh_x16  = (_Float16*)(wb + 9856);
  float*    sh_hT   = (float*)(wb + 9856);
  float*    sh_dp   = (float*)(wb + 10112);

  unsigned wr_r[32], wr_z[32], wr_n[32];  // GRU W_hh rows fp16 (96 VGPR)
  unsigned udr[16];                        // U_d (later W_d) row a, half
  float4 wo2a, wo2b;                       // W_out2 chunk for hw batch (8 VGPR)

  // ---------------- stage ----------------
  {
    const f4v* wp = (const f4v*)W_hh_e;
    #pragma unroll
    for (int k = 0; k < 16; ++k) {
      f4v vr = wp[l*16 + k];
      f4v vz = wp[(64 + l)*16 + k];
      f4v vn = wp[(128 + l)*16 + k];
      wr_r[2*k] = pk2(vr.x, vr.y); wr_r[2*k+1] = pk2(vr.z, vr.w);
      wr_z[2*k] = pk2(vz.x, vz.y); wr_z[2*k+1] = pk2(vz.z, vz.w);
      wr_n[2*k] = pk2(vn.x, vn.y); wr_n[2*k+1] = pk2(vn.z, vn.w);
    }
  }
  float wih0 = W_ih_e[l], wih1 = W_ih_e[64+l], wih2 = W_ih_e[128+l];
  float bb0  = b_ih_e[l] + b_hh_e[l];
  float bb1  = b_ih_e[64+l] + b_hh_e[64+l];
  float bih2 = b_ih_e[128+l], bhh2 = b_hh_e[128+l];
  {
    const float4* wo = (const float4*)(W_out + 64 + (l & 7)*8);
    wo2a = wo[0]; wo2b = wo[1];
  }
  {
    f2 g = ((const f2*)(x + (size_t)b * T))[l];
    ((unsigned*)sh_x16)[l] = pk2(g.x, g.y);
  }
  sh_ring[7*72 + l] = (_Float16)0.0f;    // h_{-1}
  {  // U_d row a, half -> registers
    const f2* up = (const f2*)(U_d + a*64 + half*32);
    #pragma unroll
    for (int k = 0; k < 16; ++k) { f2 f = up[k]; udr[k] = pk2(f.x, f.y); }
  }

  // ---------------- encoder: 128 steps, wave-synchronous ----------------
  // input-attention is identity (softmax over size-1 axis == 1).
  float hprev = 0.0f;
  #pragma unroll 1
  for (int t0 = 0; t0 < T; t0 += 8) {
    #pragma unroll
    for (int u = 0; u < 8; ++u) {
      const int t = t0 + u;
      float ar0=0,ar1=0,az0=0,az1=0,an0=0,an1=0;
      gru_mv(sh_ring + ((t+7)&7)*72, wr_r, wr_z, wr_n, ar0,ar1,az0,az1,an0,an1);
      float xt = (float)sh_x16[t];
      float r = fsig(fmaf(xt, wih0, bb0) + ar0 + ar1);
      float z = fsig(fmaf(xt, wih1, bb1) + az0 + az1);
      float n = ftanh(fmaf(xt, wih2, bih2) + r * (an0 + an1 + bhh2));
      hprev = fmaf(z, hprev - n, n);
      sh_ring[(t&7)*72 + l] = (_Float16)hprev;
    }
    // ---- Hp batch for t0..t0+7 ----
    #pragma unroll
    for (int k = 0; k < 8; ++k) {
      float acc = proj_dot(sh_ring + k*72 + half*32, udr);
      acc += __shfl_xor(acc, 32);
      acc *= C2;
      float accn = __shfl_down(acc, 1);
      if (l < 32 && !(l & 1))
        sh_hp[(t0+k)*HPS + (l >> 1)] = pk2(acc, accn);
    }
    // ---- hw batch for t0..t0+7 ----
    {
      int r8 = l >> 3, c8 = l & 7;
      uint4 hv = *(const uint4*)(sh_ring + r8*72 + c8*8);
      half2_t h0=bch(hv.x), h1=bch(hv.y), h2=bch(hv.z), h3=bch(hv.w);
      float p = (float)h0.x*wo2a.x;
      p = fmaf((float)h0.y, wo2a.y, p); p = fmaf((float)h1.x, wo2a.z, p);
      p = fmaf((float)h1.y, wo2a.w, p); p = fmaf((float)h2.x, wo2b.x, p);
      p = fmaf((float)h2.y, wo2b.y, p); p = fmaf((float)h3.x, wo2b.z, p);
      p = fmaf((float)h3.y, wo2b.w, p);
      p += __shfl_xor(p, 1);
      p += __shfl_xor(p, 2);
      p += __shfl_xor(p, 4);
      if (c8 == 0) sh_hp[(t0+r8)*HPS + 16] = __builtin_bit_cast(unsigned, p);
    }
  }

  // ---------------- decoder prep ----------------
  sh_hT[l] = hprev;                      // x dead; reuse region as f32 h_T
  float dprev;
  {  // d0 = h_T @ W_init.T + b_init
    const f4v* wi = (const f4v*)(W_init + l*64);
    const f4v* hb = (const f4v*)sh_hT;
    f2 a0={0,0}, a1={0,0};
    #pragma unroll
    for (int k = 0; k < 16; ++k) {
      f4v wv = wi[k]; f4v hv = hb[k];
      a0 = pkfma(wv.xy, hv.xy, a0);
      a1 = pkfma(wv.zw, hv.zw, a1);
    }
    dprev = b_init[l] + (a0.x + a0.y) + (a1.x + a1.y);
  }
  {  // reload GRU weights with decoder W_hh
    const f4v* wp = (const f4v*)W_hh_d;
    #pragma unroll
    for (int k = 0; k < 16; ++k) {
      f4v vr = wp[l*16 + k];
      f4v vz = wp[(64 + l)*16 + k];
      f4v vn = wp[(128 + l)*16 + k];
      wr_r[2*k] = pk2(vr.x, vr.y); wr_r[2*k+1] = pk2(vr.z, vr.w);
      wr_z[2*k] = pk2(vz.x, vz.y); wr_z[2*k+1] = pk2(vz.z, vz.w);
      wr_n[2*k] = pk2(vn.x, vn.y); wr_n[2*k+1] = pk2(vn.z, vn.w);
    }
  }
  wih0 = W_ih_d[l]; wih1 = W_ih_d[64+l]; wih2 = W_ih_d[128+l];
  bb0  = b_ih_d[l] + b_hh_d[l];
  bb1  = b_ih_d[64+l] + b_hh_d[64+l];
  bih2 = b_ih_d[128+l]; bhh2 = b_hh_d[128+l];
  {  // W_d row -> udr (overwrites U_d row)
    const f2* up = (const f2*)(W_d + a*64 + half*32);
    #pragma unroll
    for (int k = 0; k < 16; ++k) { f2 f = up[k]; udr[k] = pk2(f.x, f.y); }
  }
  float wout1 = W_out[l];
  float hw0 = __builtin_bit_cast(float, sh_hp[l*HPS + 16]);
  float hw1 = __builtin_bit_cast(float, sh_hp[(64 + l)*HPS + 16]);
  float oprev = y0[0];
  float bo = b_out[0];
  float c1;                              // log2e * sum(v_d)
  {
    float sv = v_d[a];
    sv += __shfl_xor(sv, 16); sv += __shfl_xor(sv, 8);
    sv += __shfl_xor(sv, 4);  sv += __shfl_xor(sv, 2); sv += __shfl_xor(sv, 1);
    c1 = LOG2E * sv;
  }
  sh_ring[l] = (_Float16)dprev;          // d fp16 in ring row 0

  const unsigned* hpr0 = sh_hp + l*HPS;
  const unsigned* hpr1 = sh_hp + (64 + l)*HPS;

  // ---------------- decoder: 24 steps, wave-synchronous ----------------
  #pragma unroll 1
  for (int s = 0; s < HOR; ++s) {
    float ar0=0,ar1=0,az0=0,az1=0,an0=0,an1=0;
    gru_mv(sh_ring, wr_r, wr_z, wr_n, ar0,ar1,az0,az1,an0,an1);
    float r = fsig(fmaf(oprev, wih0, bb0) + ar0 + ar1);
    float z = fsig(fmaf(oprev, wih1, bb1) + az0 + az1);
    float n = ftanh(fmaf(oprev, wih2, bih2) + r * (an0 + an1 + bhh2));
    float dnew = fmaf(z, dprev - n, n);
    dprev = dnew;
    sh_ring[l] = (_Float16)dnew;
    // d_proj (pre-scaled C2)
    {
      float acc = proj_dot(sh_ring + half*32, udr);
      acc += __shfl_xor(acc, 32);
      if (l < 32) sh_dp[l] = C2 * acc;
    }
    // scores rows t0=l, t1=64+l: score = SV - 2*sum_a v_a*sig2(dps+hps)
    float rs0 = 0.f, rs1 = 0.f;
    #pragma unroll
    for (int j2 = 0; j2 < 8; ++j2) {
      f4v dp = *(const f4v*)&sh_dp[4*j2];
      half2_t ha0 = bch(hpr0[2*j2]), hb0 = bch(hpr0[2*j2+1]);
      half2_t ha1 = bch(hpr1[2*j2]), hb1 = bch(hpr1[2*j2+1]);
      float v0 = v_d[4*j2], v1 = v_d[4*j2+1], v2 = v_d[4*j2+2], v3 = v_d[4*j2+3];
      rs0 = fmaf(v0, frcp(1.0f + fexp2(dp.x + (float)ha0.x)), rs0);
      rs0 = fmaf(v1, frcp(1.0f + fexp2(dp.y + (float)ha0.y)), rs0);
      rs0 = fmaf(v2, frcp(1.0f + fexp2(dp.z + (float)hb0.x)), rs0);
      rs0 = fmaf(v3, frcp(1.0f + fexp2(dp.w + (float)hb0.y)), rs0);
      rs1 = fmaf(v0, frcp(1.0f + fexp2(dp.x + (float)ha1.x)), rs1);
      rs1 = fmaf(v1, frcp(1.0f + fexp2(dp.y + (float)ha1.y)), rs1);
      rs1 = fmaf(v2, frcp(1.0f + fexp2(dp.z + (float)hb1.x)), rs1);
      rs1 = fmaf(v3, frcp(1.0f + fexp2(dp.w + (float)hb1.y)), rs1);
    }
    float e0 = fexp2(fmaf(-C2, rs0, c1));
    float e1 = fexp2(fmaf(-C2, rs1, c1));
    // three DPP reductions (VALU-rate; R11-verified)
    float P0 = rdl63(wavesum_dpp(e0 + e1));
    float P1 = rdl63(wavesum_dpp(fmaf(e0, hw0, e1 * hw1)));
    float P2 = rdl63(wavesum_dpp(wout1 * dnew));
    float o = fmaf(P1, frcp(P0), P2 + bo);
    if (l == 0) out[(size_t)b * HOR + s] = o;
    oprev = o;
  }
}

extern "C" void kernel_launch(void* const* d_in, const int* in_sizes, int n_in,
                              void* d_out, int out_size, void* d_ws, size_t ws_size,
                              hipStream_t stream) {
  const float* x      = (const float*)d_in[0];
  const float* W_ih_e = (const float*)d_in[1];
  const float* W_hh_e = (const float*)d_in[2];
  const float* b_ih_e = (const float*)d_in[3];
  const float* b_hh_e = (const float*)d_in[4];
  // d_in[5..8] = W_e, U_e, b_e, v_e : dead (softmax over size-1 axis == 1)
  const float* W_init = (const float*)d_in[9];
  const float* b_init = (const float*)d_in[10];
  const float* W_ih_d = (const float*)d_in[11];
  const float* W_hh_d = (const float*)d_in[12];
  const float* b_ih_d = (const float*)d_in[13];
  const float* b_hh_d = (const float*)d_in[14];
  const float* W_d    = (const float*)d_in[15];
  const float* U_d    = (const float*)d_in[16];
  const float* v_d    = (const float*)d_in[17];
  const float* W_out  = (const float*)d_in[18];
  const float* b_out  = (const float*)d_in[19];
  const float* y0     = (const float*)d_in[20];
  float* outp = (float*)d_out;

  darnn_kernel<<<BATCH/2, 128, 0, stream>>>(x, W_ih_e, W_hh_e, b_ih_e, b_hh_e,
      W_init, b_init, W_ih_d, W_hh_d, b_ih_d, b_hh_d, W_d, U_d, v_d, W_out,
      b_out, y0, outp);
}

// Round 13
// 397.616 us; speedup vs baseline: 1.0338x; 1.0338x over previous
//
#include <hip/hip_runtime.h>
#include <math.h>

#define BATCH 4096
#define T 128
#define HOR 24

#define LOG2E 1.44269504088896f
#define C2    2.88539008177793f   // 2*log2(e)

typedef _Float16 half2_t __attribute__((ext_vector_type(2)));
typedef _Float16 half8   __attribute__((ext_vector_type(8)));
typedef float f2  __attribute__((ext_vector_type(2)));
typedef float f4v __attribute__((ext_vector_type(4)));

__device__ __forceinline__ float fexp2(float x){ return __builtin_amdgcn_exp2f(x); }
__device__ __forceinline__ float frcp(float x){ return __builtin_amdgcn_rcpf(x); }
__device__ __forceinline__ float fsig(float x){ return frcp(1.0f + fexp2(-LOG2E*x)); }
__device__ __forceinline__ float ftanh(float x){ return fmaf(-2.0f, frcp(1.0f + fexp2(C2*x)), 1.0f); }
__device__ __forceinline__ half2_t bch(unsigned u){ return __builtin_bit_cast(half2_t,u); }
__device__ __forceinline__ unsigned pk2(float a,float b){ return __builtin_bit_cast(unsigned, __builtin_amdgcn_cvt_pkrtz(a,b)); }
__device__ __forceinline__ float fdot2f(half2_t a, half2_t b, float c){
#if __has_builtin(__builtin_amdgcn_fdot2)
  return __builtin_amdgcn_fdot2(a,b,c,false);
#else
  return fmaf((float)a.x,(float)b.x, fmaf((float)a.y,(float)b.y,c));
#endif
}
__device__ __forceinline__ f2 pkfma(f2 a, f2 b, f2 c){ return __builtin_elementwise_fma(a,b,c); }

template <int CTRL, int RMASK>
__device__ __forceinline__ float dpp_add(float v) {
  int s = __builtin_amdgcn_update_dpp(0, __builtin_bit_cast(int, v), CTRL, RMASK, 0xf, true);
  return v + __builtin_bit_cast(float, s);
}
__device__ __forceinline__ float wavesum_dpp(float v) {
  v = dpp_add<0x111, 0xf>(v);
  v = dpp_add<0x112, 0xf>(v);
  v = dpp_add<0x114, 0xf>(v);
  v = dpp_add<0x118, 0xf>(v);
  v = dpp_add<0x142, 0xa>(v);
  v = dpp_add<0x143, 0xc>(v);
  return v;                     // total in lane 63
}
__device__ __forceinline__ float rdl63(float v){
  return __builtin_bit_cast(float, __builtin_amdgcn_readlane(__builtin_bit_cast(int, v), 63));
}

__device__ __forceinline__ void gru_mv(const _Float16* hrow,
    const unsigned* wr_r, const unsigned* wr_z, const unsigned* wr_n,
    float& ar0, float& ar1, float& az0, float& az1, float& an0, float& an1)
{
  const uint4* hq = (const uint4*)hrow;
  #pragma unroll
  for (int q = 0; q < 8; ++q) {
    uint4 hv = hq[q];
    ar0 = fdot2f(bch(hv.x), bch(wr_r[4*q+0]), ar0);
    az0 = fdot2f(bch(hv.x), bch(wr_z[4*q+0]), az0);
    an0 = fdot2f(bch(hv.x), bch(wr_n[4*q+0]), an0);
    ar1 = fdot2f(bch(hv.y), bch(wr_r[4*q+1]), ar1);
    az1 = fdot2f(bch(hv.y), bch(wr_z[4*q+1]), az1);
    an1 = fdot2f(bch(hv.y), bch(wr_n[4*q+1]), an1);
    ar0 = fdot2f(bch(hv.z), bch(wr_r[4*q+2]), ar0);
    az0 = fdot2f(bch(hv.z), bch(wr_z[4*q+2]), az0);
    an0 = fdot2f(bch(hv.z), bch(wr_n[4*q+2]), an0);
    ar1 = fdot2f(bch(hv.w), bch(wr_r[4*q+3]), ar1);
    az1 = fdot2f(bch(hv.w), bch(wr_z[4*q+3]), az1);
    an1 = fdot2f(bch(hv.w), bch(wr_n[4*q+3]), an1);
  }
}

__device__ __forceinline__ float proj_dot(const _Float16* base, const unsigned* udr)
{
  float acc = 0.f;
  const uint4* hb = (const uint4*)base;
  #pragma unroll
  for (int q = 0; q < 4; ++q) {
    uint4 hv = hb[q];
    acc = fdot2f(bch(hv.x), bch(udr[4*q+0]), acc);
    acc = fdot2f(bch(hv.y), bch(udr[4*q+1]), acc);
    acc = fdot2f(bch(hv.z), bch(udr[4*q+2]), acc);
    acc = fdot2f(bch(hv.w), bch(udr[4*q+3]), acc);
  }
  return acc;
}

__device__ __forceinline__ half8 cvt8(f4v a, f4v b){
  half8 h;
  h[0]=(_Float16)a.x; h[1]=(_Float16)a.y; h[2]=(_Float16)a.z; h[3]=(_Float16)a.w;
  h[4]=(_Float16)b.x; h[5]=(_Float16)b.y; h[6]=(_Float16)b.z; h[7]=(_Float16)b.w;
  return h;
}

// ============ Kernel A: encoder, 16 elements/wave via MFMA GRU ============
// gates(192x16) = W_hh(192x64) . H(64x16) as 24 mfma_f32_16x16x32_f16/step:
// the MFMA array performs the h-broadcast that cost ~100 LDS-pipe cyc/elem/step
// in the R6-R12 structure (the invariant 405us wall = LDS-pipe/queueing bound
// at 16 resident elems/CU). Hp/hw/h_T stream to global for the decoder kernel.
// C/D map (m89-verified): col=lane&15 (=element), row=(lane>>4)*4+reg.
// A: [m=lane&15][k=quad*8+j]; B: [k=quad*8+j][n=lane&15]. Grid 256 x 64thr.
__global__ __launch_bounds__(64, 1)
void darnn_enc(const float* __restrict__ x,
               const float* __restrict__ W_ih_e, const float* __restrict__ W_hh_e,
               const float* __restrict__ b_ih_e, const float* __restrict__ b_hh_e,
               const float* __restrict__ U_d, const float* __restrict__ W_out,
               unsigned* __restrict__ hpG, float* __restrict__ hTG)
{
  const int l = threadIdx.x;
  const int c = l & 15;          // MFMA column = element slot
  const int q = l >> 4;          // quad
  const int e0 = blockIdx.x * 16;

  __shared__ __align__(16) _Float16 He[16*72];   // h[e][k] fp16, pad 72 (2-way banks)
  __shared__ __align__(16) unsigned xw[16*65];   // x fp16-pairs [e][65 uints]

  // ---- stage x (fp32 -> fp16 LDS) ----
  #pragma unroll 1
  for (int e = 0; e < 16; ++e) {
    f2 g = ((const f2*)(x + (size_t)(e0+e)*T))[l];
    xw[e*65 + l] = pk2(g.x, g.y);
  }
  // ---- zero He (h_{-1} = 0): 576 uints ----
  #pragma unroll
  for (int i = 0; i < 9; ++i) ((unsigned*)He)[i*64 + l] = 0;

  // ---- A-frags: W_hh rows (96 VGPR; budget 512 at (64,1) -> no spill) ----
  half8 Whh[12][2];
  #pragma unroll
  for (int tau = 0; tau < 12; ++tau)
    #pragma unroll
    for (int kap = 0; kap < 2; ++kap) {
      const f4v* p = (const f4v*)(W_hh_e + (size_t)(16*tau + c)*64 + 32*kap + 8*q);
      Whh[tau][kap] = cvt8(p[0], p[1]);
    }
  // ---- U_d frags (pre-scaled C2) + wo2 frags ----
  half8 AU[2][2], AW[2];
  #pragma unroll
  for (int mu = 0; mu < 2; ++mu)
    #pragma unroll
    for (int kap = 0; kap < 2; ++kap) {
      const f4v* p = (const f4v*)(U_d + (size_t)(16*mu + c)*64 + 32*kap + 8*q);
      f4v w0 = p[0], w1 = p[1];
      AU[mu][kap] = cvt8(w0 * C2, w1 * C2);
    }
  #pragma unroll
  for (int kap = 0; kap < 2; ++kap) {
    half8 h = {0,0,0,0,0,0,0,0};
    if (c == 0) {
      const f4v* p = (const f4v*)(W_out + 64 + 32*kap + 8*q);
      h = cvt8(p[0], p[1]);
    }
    AW[kap] = h;
  }
  // ---- per-lane bias/W_ih regs [tau][i], m0 = 16*tau + 4*q + i ----
  f4v wih0[4], wih1[4], wih2[4], bb0[4], bb1[4], bi2[4], bh2[4];
  #pragma unroll
  for (int tau = 0; tau < 4; ++tau) {
    int m0 = 16*tau + 4*q;
    wih0[tau] = *(const f4v*)(W_ih_e + m0);
    wih1[tau] = *(const f4v*)(W_ih_e + 64 + m0);
    wih2[tau] = *(const f4v*)(W_ih_e + 128 + m0);
    bb0[tau]  = *(const f4v*)(b_ih_e + m0)      + *(const f4v*)(b_hh_e + m0);
    bb1[tau]  = *(const f4v*)(b_ih_e + 64 + m0) + *(const f4v*)(b_hh_e + 64 + m0);
    bi2[tau]  = *(const f4v*)(b_ih_e + 128 + m0);
    bh2[tau]  = *(const f4v*)(b_hh_e + 128 + m0);
  }
  f4v hreg[4] = {{0,0,0,0},{0,0,0,0},{0,0,0,0},{0,0,0,0}};
  const f4v z4 = {0,0,0,0};
  unsigned* hpB = hpG + (size_t)(e0 + c) * 2176;

  // ---- 128 steps (single wave per block: LDS in-order, zero barriers) ----
  #pragma unroll 1
  for (int t = 0; t < T; ++t) {
    half8 B0 = __builtin_bit_cast(half8, *(const uint4*)(He + c*72 + 8*q));
    half8 B1 = __builtin_bit_cast(half8, *(const uint4*)(He + c*72 + 32 + 8*q));
    // Hp[t-1], hw[t-1] from h_{t-1} (currently in B-frags)
    if (t > 0) {
      f4v cu0 = __builtin_amdgcn_mfma_f32_16x16x32_f16(AU[0][0], B0, z4, 0,0,0);
      cu0     = __builtin_amdgcn_mfma_f32_16x16x32_f16(AU[0][1], B1, cu0, 0,0,0);
      f4v cu1 = __builtin_amdgcn_mfma_f32_16x16x32_f16(AU[1][0], B0, z4, 0,0,0);
      cu1     = __builtin_amdgcn_mfma_f32_16x16x32_f16(AU[1][1], B1, cu1, 0,0,0);
      f4v cw  = __builtin_amdgcn_mfma_f32_16x16x32_f16(AW[0],    B0, z4, 0,0,0);
      cw      = __builtin_amdgcn_mfma_f32_16x16x32_f16(AW[1],    B1, cw, 0,0,0);
      unsigned* hpE = hpB + (t-1)*17;
      hpE[2*q]   = pk2(cu0[0], cu0[1]);
      hpE[2*q+1] = pk2(cu0[2], cu0[3]);
      hpE[8+2*q] = pk2(cu1[0], cu1[1]);
      hpE[9+2*q] = pk2(cu1[2], cu1[3]);
      if (q == 0) ((float*)hpE)[16] = cw[0];
    }
    // GRU gates via MFMA
    f4v g[12];
    #pragma unroll
    for (int tau = 0; tau < 12; ++tau) {
      g[tau] = __builtin_amdgcn_mfma_f32_16x16x32_f16(Whh[tau][0], B0, z4, 0,0,0);
      g[tau] = __builtin_amdgcn_mfma_f32_16x16x32_f16(Whh[tau][1], B1, g[tau], 0,0,0);
    }
    float xc = (float)((const _Float16*)xw)[c*130 + t];
    // combine (all three gates for (m,e) land in the SAME lane)
    #pragma unroll
    for (int tau = 0; tau < 4; ++tau) {
      f4v gr = g[tau], gz = g[tau+4], gn = g[tau+8];
      f4v hn;
      #pragma unroll
      for (int i = 0; i < 4; ++i) {
        float r  = fsig(fmaf(xc, wih0[tau][i], bb0[tau][i]) + gr[i]);
        float zf = fsig(fmaf(xc, wih1[tau][i], bb1[tau][i]) + gz[i]);
        float n  = ftanh(fmaf(xc, wih2[tau][i], bi2[tau][i]) + r*(gn[i] + bh2[tau][i]));
        float h  = fmaf(zf, hreg[tau][i] - n, n);
        hreg[tau][i] = h;
        hn[i] = h;
      }
      uint2 w; w.x = pk2(hn[0], hn[1]); w.y = pk2(hn[2], hn[3]);
      *(uint2*)(He + c*72 + 16*tau + 4*q) = w;
    }
  }
  // ---- epilogue: Hp[127], hw[127] from h_127 ----
  {
    half8 B0 = __builtin_bit_cast(half8, *(const uint4*)(He + c*72 + 8*q));
    half8 B1 = __builtin_bit_cast(half8, *(const uint4*)(He + c*72 + 32 + 8*q));
    f4v cu0 = __builtin_amdgcn_mfma_f32_16x16x32_f16(AU[0][0], B0, z4, 0,0,0);
    cu0     = __builtin_amdgcn_mfma_f32_16x16x32_f16(AU[0][1], B1, cu0, 0,0,0);
    f4v cu1 = __builtin_amdgcn_mfma_f32_16x16x32_f16(AU[1][0], B0, z4, 0,0,0);
    cu1     = __builtin_amdgcn_mfma_f32_16x16x32_f16(AU[1][1], B1, cu1, 0,0,0);
    f4v cw  = __builtin_amdgcn_mfma_f32_16x16x32_f16(AW[0],    B0, z4, 0,0,0);
    cw      = __builtin_amdgcn_mfma_f32_16x16x32_f16(AW[1],    B1, cw, 0,0,0);
    unsigned* hpE = hpB + 127*17;
    hpE[2*q]   = pk2(cu0[0], cu0[1]);
    hpE[2*q+1] = pk2(cu0[2], cu0[3]);
    hpE[8+2*q] = pk2(cu1[0], cu1[1]);
    hpE[9+2*q] = pk2(cu1[2], cu1[3]);
    if (q == 0) ((float*)hpE)[16] = cw[0];
  }
  // ---- h_T (fp32) for decoder d0 ----
  #pragma unroll
  for (int tau = 0; tau < 4; ++tau)
    #pragma unroll
    for (int i = 0; i < 4; ++i)
      hTG[(size_t)(e0 + c)*64 + 16*tau + 4*q + i] = hreg[tau][i];
}

// ============ Kernel B: decoder — the PROVEN R12 decoder, hp from global ====
__global__ __launch_bounds__(128, 2)
void darnn_dec(const float* __restrict__ W_init, const float* __restrict__ b_init,
               const float* __restrict__ W_ih_d, const float* __restrict__ W_hh_d,
               const float* __restrict__ b_ih_d, const float* __restrict__ b_hh_d,
               const float* __restrict__ W_d, const float* __restrict__ v_d,
               const float* __restrict__ W_out, const float* __restrict__ b_out,
               const float* __restrict__ y0,
               const unsigned* __restrict__ hpG, const float* __restrict__ hTG,
               float* __restrict__ out)
{
  const int tid = threadIdx.x;
  const int wid = tid >> 6;
  const int l   = tid & 63;
  const int b   = 2*blockIdx.x + wid;
  const int a    = l & 31;
  const int half = l >> 5;

  // per-wave slice 9248 B: hp[0,8704) ring@8704 hT@8864 dp@9120
  __shared__ __align__(16) unsigned char smem[18496];
  unsigned char* wbp = smem + wid*9248;
  unsigned* sh_hp   = (unsigned*)wbp;
  _Float16* sh_ring = (_Float16*)(wbp + 8704);
  float*    sh_hT   = (float*)(wbp + 8864);
  float*    sh_dp   = (float*)(wbp + 9120);

  // ---- stage hp image (2176 uints) + hT ----
  {
    const uint4* src = (const uint4*)(hpG + (size_t)b * 2176);
    #pragma unroll
    for (int it = 0; it < 8; ++it)
      ((uint4*)sh_hp)[it*64 + l] = src[it*64 + l];
    const unsigned* s2 = hpG + (size_t)b*2176 + 2048;
    sh_hp[2048 + l] = s2[l];
    sh_hp[2112 + l] = s2[64 + l];
  }
  sh_hT[l] = hTG[(size_t)b*64 + l];

  unsigned wr_r[32], wr_z[32], wr_n[32];
  {
    const f4v* wp = (const f4v*)W_hh_d;
    #pragma unroll
    for (int k = 0; k < 16; ++k) {
      f4v vr = wp[l*16 + k];
      f4v vz = wp[(64 + l)*16 + k];
      f4v vn = wp[(128 + l)*16 + k];
      wr_r[2*k] = pk2(vr.x, vr.y); wr_r[2*k+1] = pk2(vr.z, vr.w);
      wr_z[2*k] = pk2(vz.x, vz.y); wr_z[2*k+1] = pk2(vz.z, vz.w);
      wr_n[2*k] = pk2(vn.x, vn.y); wr_n[2*k+1] = pk2(vn.z, vn.w);
    }
  }
  float wih0 = W_ih_d[l], wih1 = W_ih_d[64+l], wih2 = W_ih_d[128+l];
  float bb0  = b_ih_d[l] + b_hh_d[l];
  float bb1  = b_ih_d[64+l] + b_hh_d[64+l];
  float bih2 = b_ih_d[128+l], bhh2 = b_hh_d[128+l];
  unsigned udr[16];
  {
    const f2* up = (const f2*)(W_d + a*64 + half*32);
    #pragma unroll
    for (int k = 0; k < 16; ++k) { f2 f = up[k]; udr[k] = pk2(f.x, f.y); }
  }
  float dprev;
  {  // d0 = h_T @ W_init.T + b_init
    const f4v* wi = (const f4v*)(W_init + l*64);
    const f4v* hb = (const f4v*)sh_hT;
    f2 a0={0,0}, a1={0,0};
    #pragma unroll
    for (int k = 0; k < 16; ++k) {
      f4v wv = wi[k]; f4v hv = hb[k];
      a0 = pkfma(wv.xy, hv.xy, a0);
      a1 = pkfma(wv.zw, hv.zw, a1);
    }
    dprev = b_init[l] + (a0.x + a0.y) + (a1.x + a1.y);
  }
  float wout1 = W_out[l];
  float hw0 = __builtin_bit_cast(float, sh_hp[l*17 + 16]);
  float hw1 = __builtin_bit_cast(float, sh_hp[(64 + l)*17 + 16]);
  float oprev = y0[0];
  float bo = b_out[0];
  float c1;
  {
    float sv = v_d[a];
    sv += __shfl_xor(sv, 16); sv += __shfl_xor(sv, 8);
    sv += __shfl_xor(sv, 4);  sv += __shfl_xor(sv, 2); sv += __shfl_xor(sv, 1);
    c1 = LOG2E * sv;
  }
  sh_ring[l] = (_Float16)dprev;

  const unsigned* hpr0 = sh_hp + l*17;
  const unsigned* hpr1 = sh_hp + (64 + l)*17;

  #pragma unroll 1
  for (int s = 0; s < HOR; ++s) {
    float ar0=0,ar1=0,az0=0,az1=0,an0=0,an1=0;
    gru_mv(sh_ring, wr_r, wr_z, wr_n, ar0,ar1,az0,az1,an0,an1);
    float r = fsig(fmaf(oprev, wih0, bb0) + ar0 + ar1);
    float z = fsig(fmaf(oprev, wih1, bb1) + az0 + az1);
    float n = ftanh(fmaf(oprev, wih2, bih2) + r * (an0 + an1 + bhh2));
    float dnew = fmaf(z, dprev - n, n);
    dprev = dnew;
    sh_ring[l] = (_Float16)dnew;
    {
      float acc = proj_dot(sh_ring + half*32, udr);
      acc += __shfl_xor(acc, 32);
      if (l < 32) sh_dp[l] = C2 * acc;
    }
    float rs0 = 0.f, rs1 = 0.f;
    #pragma unroll
    for (int j2 = 0; j2 < 8; ++j2) {
      f4v dp = *(const f4v*)&sh_dp[4*j2];
      half2_t ha0 = bch(hpr0[2*j2]), hb0 = bch(hpr0[2*j2+1]);
      half2_t ha1 = bch(hpr1[2*j2]), hb1 = bch(hpr1[2*j2+1]);
      float v0 = v_d[4*j2], v1 = v_d[4*j2+1], v2 = v_d[4*j2+2], v3 = v_d[4*j2+3];
      rs0 = fmaf(v0, frcp(1.0f + fexp2(dp.x + (float)ha0.x)), rs0);
      rs0 = fmaf(v1, frcp(1.0f + fexp2(dp.y + (float)ha0.y)), rs0);
      rs0 = fmaf(v2, frcp(1.0f + fexp2(dp.z + (float)hb0.x)), rs0);
      rs0 = fmaf(v3, frcp(1.0f + fexp2(dp.w + (float)hb0.y)), rs0);
      rs1 = fmaf(v0, frcp(1.0f + fexp2(dp.x + (float)ha1.x)), rs1);
      rs1 = fmaf(v1, frcp(1.0f + fexp2(dp.y + (float)ha1.y)), rs1);
      rs1 = fmaf(v2, frcp(1.0f + fexp2(dp.z + (float)hb1.x)), rs1);
      rs1 = fmaf(v3, frcp(1.0f + fexp2(dp.w + (float)hb1.y)), rs1);
    }
    float e0 = fexp2(fmaf(-C2, rs0, c1));
    float e1 = fexp2(fmaf(-C2, rs1, c1));
    float P0 = rdl63(wavesum_dpp(e0 + e1));
    float P1 = rdl63(wavesum_dpp(fmaf(e0, hw0, e1 * hw1)));
    float P2 = rdl63(wavesum_dpp(wout1 * dnew));
    float o = fmaf(P1, frcp(P0), P2 + bo);
    if (l == 0) out[(size_t)b * HOR + s] = o;
    oprev = o;
  }
}

extern "C" void kernel_launch(void* const* d_in, const int* in_sizes, int n_in,
                              void* d_out, int out_size, void* d_ws, size_t ws_size,
                              hipStream_t stream) {
  const float* x      = (const float*)d_in[0];
  const float* W_ih_e = (const float*)d_in[1];
  const float* W_hh_e = (const float*)d_in[2];
  const float* b_ih_e = (const float*)d_in[3];
  const float* b_hh_e = (const float*)d_in[4];
  // d_in[5..8] = W_e, U_e, b_e, v_e : dead (softmax over size-1 axis == 1)
  const float* W_init = (const float*)d_in[9];
  const float* b_init = (const float*)d_in[10];
  const float* W_ih_d = (const float*)d_in[11];
  const float* W_hh_d = (const float*)d_in[12];
  const float* b_ih_d = (const float*)d_in[13];
  const float* b_hh_d = (const float*)d_in[14];
  const float* W_d    = (const float*)d_in[15];
  const float* U_d    = (const float*)d_in[16];
  const float* v_d    = (const float*)d_in[17];
  const float* W_out  = (const float*)d_in[18];
  const float* b_out  = (const float*)d_in[19];
  const float* y0     = (const float*)d_in[20];
  float* outp = (float*)d_out;

  // workspace: hp images (4096 x 8704 B = 35.65 MB) + h_T (1 MB)
  unsigned* hpG = (unsigned*)d_ws;
  float*    hTG = (float*)((char*)d_ws + (size_t)BATCH * 2176 * 4);

  darnn_enc<<<BATCH/16, 64, 0, stream>>>(x, W_ih_e, W_hh_e, b_ih_e, b_hh_e,
      U_d, W_out, hpG, hTG);
  darnn_dec<<<BATCH/2, 128, 0, stream>>>(W_init, b_init, W_ih_d, W_hh_d,
      b_ih_d, b_hh_d, W_d, v_d, W_out, b_out, y0, hpG, hTG, outp);
}

// Round 14
// 291.392 us; speedup vs baseline: 1.4107x; 1.3645x over previous
//
#include <hip/hip_runtime.h>
#include <math.h>

#define BATCH 4096
#define T 128
#define HOR 24

#define LOG2E 1.44269504088896f
#define C2    2.88539008177793f   // 2*log2(e)

typedef _Float16 half2_t __attribute__((ext_vector_type(2)));
typedef _Float16 half8   __attribute__((ext_vector_type(8)));
typedef float f2  __attribute__((ext_vector_type(2)));
typedef float f4v __attribute__((ext_vector_type(4)));

__device__ __forceinline__ float fexp2(float x){ return __builtin_amdgcn_exp2f(x); }
__device__ __forceinline__ float frcp(float x){ return __builtin_amdgcn_rcpf(x); }
__device__ __forceinline__ float fsig(float x){ return frcp(1.0f + fexp2(-LOG2E*x)); }
__device__ __forceinline__ float ftanh(float x){ return fmaf(-2.0f, frcp(1.0f + fexp2(C2*x)), 1.0f); }
__device__ __forceinline__ half2_t bch(unsigned u){ return __builtin_bit_cast(half2_t,u); }
__device__ __forceinline__ unsigned pk2(float a,float b){ return __builtin_bit_cast(unsigned, __builtin_amdgcn_cvt_pkrtz(a,b)); }
__device__ __forceinline__ float fdot2f(half2_t a, half2_t b, float c){
#if __has_builtin(__builtin_amdgcn_fdot2)
  return __builtin_amdgcn_fdot2(a,b,c,false);
#else
  return fmaf((float)a.x,(float)b.x, fmaf((float)a.y,(float)b.y,c));
#endif
}
__device__ __forceinline__ f2 pkfma(f2 a, f2 b, f2 c){ return __builtin_elementwise_fma(a,b,c); }

template <int CTRL, int RMASK>
__device__ __forceinline__ float dpp_add(float v) {
  int s = __builtin_amdgcn_update_dpp(0, __builtin_bit_cast(int, v), CTRL, RMASK, 0xf, true);
  return v + __builtin_bit_cast(float, s);
}
__device__ __forceinline__ float wavesum_dpp(float v) {
  v = dpp_add<0x111, 0xf>(v);
  v = dpp_add<0x112, 0xf>(v);
  v = dpp_add<0x114, 0xf>(v);
  v = dpp_add<0x118, 0xf>(v);
  v = dpp_add<0x142, 0xa>(v);
  v = dpp_add<0x143, 0xc>(v);
  return v;                     // total in lane 63
}
__device__ __forceinline__ float rdl63(float v){
  return __builtin_bit_cast(float, __builtin_amdgcn_readlane(__builtin_bit_cast(int, v), 63));
}

__device__ __forceinline__ void gru_mv(const _Float16* hrow,
    const unsigned* wr_r, const unsigned* wr_z, const unsigned* wr_n,
    float& ar0, float& ar1, float& az0, float& az1, float& an0, float& an1)
{
  const uint4* hq = (const uint4*)hrow;
  #pragma unroll
  for (int q = 0; q < 8; ++q) {
    uint4 hv = hq[q];
    ar0 = fdot2f(bch(hv.x), bch(wr_r[4*q+0]), ar0);
    az0 = fdot2f(bch(hv.x), bch(wr_z[4*q+0]), az0);
    an0 = fdot2f(bch(hv.x), bch(wr_n[4*q+0]), an0);
    ar1 = fdot2f(bch(hv.y), bch(wr_r[4*q+1]), ar1);
    az1 = fdot2f(bch(hv.y), bch(wr_z[4*q+1]), az1);
    an1 = fdot2f(bch(hv.y), bch(wr_n[4*q+1]), an1);
    ar0 = fdot2f(bch(hv.z), bch(wr_r[4*q+2]), ar0);
    az0 = fdot2f(bch(hv.z), bch(wr_z[4*q+2]), az0);
    an0 = fdot2f(bch(hv.z), bch(wr_n[4*q+2]), an0);
    ar1 = fdot2f(bch(hv.w), bch(wr_r[4*q+3]), ar1);
    az1 = fdot2f(bch(hv.w), bch(wr_z[4*q+3]), az1);
    an1 = fdot2f(bch(hv.w), bch(wr_n[4*q+3]), an1);
  }
}

__device__ __forceinline__ float proj_dot(const _Float16* base, const unsigned* udr)
{
  float acc = 0.f;
  const uint4* hb = (const uint4*)base;
  #pragma unroll
  for (int q = 0; q < 4; ++q) {
    uint4 hv = hb[q];
    acc = fdot2f(bch(hv.x), bch(udr[4*q+0]), acc);
    acc = fdot2f(bch(hv.y), bch(udr[4*q+1]), acc);
    acc = fdot2f(bch(hv.z), bch(udr[4*q+2]), acc);
    acc = fdot2f(bch(hv.w), bch(udr[4*q+3]), acc);
  }
  return acc;
}

__device__ __forceinline__ half8 cvt8(f4v a, f4v b){
  half8 h;
  h[0]=(_Float16)a.x; h[1]=(_Float16)a.y; h[2]=(_Float16)a.z; h[3]=(_Float16)a.w;
  h[4]=(_Float16)b.x; h[5]=(_Float16)b.y; h[6]=(_Float16)b.z; h[7]=(_Float16)b.w;
  return h;
}

// ============ Kernel A: encoder, 16 elems/block, 4 waves (m-split) =========
// R13 post-mortem: 1-wave blocks -> 1 wave/CU (Occupancy 2.87%), 3 of 4 SIMDs
// idle. R14: gates(192x16) output rows split across 4 waves (wave w owns
// m in [16w,16w+16), 6 MFMAs/step); h ping-pongs through LDS with ONE
// __syncthreads per step. Hp/hw MFMAs distributed to waves 0/1/2, computed at
// the top of step t+1 from h_t B-frags; hpG layout identical to R13 (decoder
// unchanged/proven). Grid 256 x 256thr -> 4 waves/CU (one per SIMD).
__global__ __launch_bounds__(256, 1)
void darnn_enc(const float* __restrict__ x,
               const float* __restrict__ W_ih_e, const float* __restrict__ W_hh_e,
               const float* __restrict__ b_ih_e, const float* __restrict__ b_hh_e,
               const float* __restrict__ U_d, const float* __restrict__ W_out,
               unsigned* __restrict__ hpG, float* __restrict__ hTG)
{
  const int tid = threadIdx.x;
  const int w = tid >> 6;        // wave 0..3: owns hidden units [16w,16w+16)
  const int l = tid & 63;
  const int c = l & 15;          // MFMA column = element slot
  const int q = l >> 4;          // quad
  const int e0 = blockIdx.x * 16;
  const int m0 = 16*w + 4*q;     // first of this lane's 4 hidden units

  __shared__ __align__(16) _Float16 He[2][16*72]; // ping-pong h[e][k], pad 72
  __shared__ __align__(16) unsigned xw[16*65];    // x fp16-pairs [e][65]

  // ---- stage x + zero He[0] (cooperative, all 256 threads) ----
  for (int idx = tid; idx < 16*64; idx += 256) {
    int e = idx >> 6, j = idx & 63;
    f2 g = ((const f2*)(x + (size_t)(e0+e)*T))[j];
    xw[e*65 + j] = pk2(g.x, g.y);
  }
  for (int idx = tid; idx < 576; idx += 256) ((unsigned*)He[0])[idx] = 0;

  // ---- A-frags: this wave's W_hh rows (r/z/n), 6 half8 ----
  half8 Ar[2], Az[2], An[2];
  #pragma unroll
  for (int kap = 0; kap < 2; ++kap) {
    const f4v* pr = (const f4v*)(W_hh_e + (size_t)(16*w + c)*64       + 32*kap + 8*q);
    const f4v* pz = (const f4v*)(W_hh_e + (size_t)(64 + 16*w + c)*64  + 32*kap + 8*q);
    const f4v* pn = (const f4v*)(W_hh_e + (size_t)(128 + 16*w + c)*64 + 32*kap + 8*q);
    Ar[kap] = cvt8(pr[0], pr[1]);
    Az[kap] = cvt8(pz[0], pz[1]);
    An[kap] = cvt8(pn[0], pn[1]);
  }
  // ---- Hp/hw A-frags: wave0 -> U_d rows 0..15 (xC2), wave1 -> rows 16..31,
  //      wave2 -> W_out2 (row 0 only), wave3 -> none ----
  half8 AX[2] = {{0,0,0,0,0,0,0,0},{0,0,0,0,0,0,0,0}};
  if (w < 2) {
    #pragma unroll
    for (int kap = 0; kap < 2; ++kap) {
      const f4v* p = (const f4v*)(U_d + (size_t)(16*w + c)*64 + 32*kap + 8*q);
      AX[kap] = cvt8(p[0] * C2, p[1] * C2);
    }
  } else if (w == 2 && c == 0) {
    #pragma unroll
    for (int kap = 0; kap < 2; ++kap) {
      const f4v* p = (const f4v*)(W_out + 64 + 32*kap + 8*q);
      AX[kap] = cvt8(p[0], p[1]);
    }
  }
  // ---- per-lane combine params for m0..m0+3 ----
  f4v wih0 = *(const f4v*)(W_ih_e + m0);
  f4v wih1 = *(const f4v*)(W_ih_e + 64 + m0);
  f4v wih2 = *(const f4v*)(W_ih_e + 128 + m0);
  f4v bb0  = *(const f4v*)(b_ih_e + m0)      + *(const f4v*)(b_hh_e + m0);
  f4v bb1  = *(const f4v*)(b_ih_e + 64 + m0) + *(const f4v*)(b_hh_e + 64 + m0);
  f4v bi2  = *(const f4v*)(b_ih_e + 128 + m0);
  f4v bh2  = *(const f4v*)(b_hh_e + 128 + m0);
  f4v hreg = {0,0,0,0};
  const f4v z4 = {0,0,0,0};
  unsigned* hpB = hpG + (size_t)(e0 + c) * 2176;

  __syncthreads();

  // ---- 128 steps: read He[t&1], write He[(t+1)&1], 1 barrier/step ----
  #pragma unroll 1
  for (int t = 0; t < T; ++t) {
    const _Float16* Hc = He[t & 1];
    half8 B0 = __builtin_bit_cast(half8, *(const uint4*)(Hc + c*72 + 8*q));
    half8 B1 = __builtin_bit_cast(half8, *(const uint4*)(Hc + c*72 + 32 + 8*q));
    if (t > 0) {           // Hp/hw for t-1 from h_{t-1} (= the B-frags)
      if (w < 2) {
        f4v cu = __builtin_amdgcn_mfma_f32_16x16x32_f16(AX[0], B0, z4, 0,0,0);
        cu     = __builtin_amdgcn_mfma_f32_16x16x32_f16(AX[1], B1, cu, 0,0,0);
        unsigned* hpE = hpB + (t-1)*17 + 8*w;
        hpE[2*q]   = pk2(cu[0], cu[1]);
        hpE[2*q+1] = pk2(cu[2], cu[3]);
      } else if (w == 2) {
        f4v cw = __builtin_amdgcn_mfma_f32_16x16x32_f16(AX[0], B0, z4, 0,0,0);
        cw     = __builtin_amdgcn_mfma_f32_16x16x32_f16(AX[1], B1, cw, 0,0,0);
        if (q == 0) ((float*)(hpB + (t-1)*17))[16] = cw[0];
      }
    }
    f4v gr = __builtin_amdgcn_mfma_f32_16x16x32_f16(Ar[0], B0, z4, 0,0,0);
    gr     = __builtin_amdgcn_mfma_f32_16x16x32_f16(Ar[1], B1, gr, 0,0,0);
    f4v gz = __builtin_amdgcn_mfma_f32_16x16x32_f16(Az[0], B0, z4, 0,0,0);
    gz     = __builtin_amdgcn_mfma_f32_16x16x32_f16(Az[1], B1, gz, 0,0,0);
    f4v gn = __builtin_amdgcn_mfma_f32_16x16x32_f16(An[0], B0, z4, 0,0,0);
    gn     = __builtin_amdgcn_mfma_f32_16x16x32_f16(An[1], B1, gn, 0,0,0);
    float xc = (float)((const _Float16*)xw)[c*130 + t];
    f4v hn;
    #pragma unroll
    for (int i = 0; i < 4; ++i) {
      float r  = fsig(fmaf(xc, wih0[i], bb0[i]) + gr[i]);
      float zf = fsig(fmaf(xc, wih1[i], bb1[i]) + gz[i]);
      float n  = ftanh(fmaf(xc, wih2[i], bi2[i]) + r*(gn[i] + bh2[i]));
      float h  = fmaf(zf, hreg[i] - n, n);
      hreg[i] = h;
      hn[i] = h;
    }
    uint2 wv; wv.x = pk2(hn[0], hn[1]); wv.y = pk2(hn[2], hn[3]);
    *(uint2*)(He[(t+1)&1] + c*72 + m0) = wv;
    __syncthreads();
  }
  // ---- epilogue: Hp/hw for t=127 from He[0] (= h_127) ----
  {
    const _Float16* Hc = He[0];
    half8 B0 = __builtin_bit_cast(half8, *(const uint4*)(Hc + c*72 + 8*q));
    half8 B1 = __builtin_bit_cast(half8, *(const uint4*)(Hc + c*72 + 32 + 8*q));
    if (w < 2) {
      f4v cu = __builtin_amdgcn_mfma_f32_16x16x32_f16(AX[0], B0, z4, 0,0,0);
      cu     = __builtin_amdgcn_mfma_f32_16x16x32_f16(AX[1], B1, cu, 0,0,0);
      unsigned* hpE = hpB + 127*17 + 8*w;
      hpE[2*q]   = pk2(cu[0], cu[1]);
      hpE[2*q+1] = pk2(cu[2], cu[3]);
    } else if (w == 2) {
      f4v cw = __builtin_amdgcn_mfma_f32_16x16x32_f16(AX[0], B0, z4, 0,0,0);
      cw     = __builtin_amdgcn_mfma_f32_16x16x32_f16(AX[1], B1, cw, 0,0,0);
      if (q == 0) ((float*)(hpB + 127*17))[16] = cw[0];
    }
  }
  // ---- h_T (fp32) ----
  #pragma unroll
  for (int i = 0; i < 4; ++i)
    hTG[(size_t)(e0 + c)*64 + m0 + i] = hreg[i];
}

// ============ Kernel B: decoder — PROVEN R13 decoder, unchanged ============
__global__ __launch_bounds__(128, 2)
void darnn_dec(const float* __restrict__ W_init, const float* __restrict__ b_init,
               const float* __restrict__ W_ih_d, const float* __restrict__ W_hh_d,
               const float* __restrict__ b_ih_d, const float* __restrict__ b_hh_d,
               const float* __restrict__ W_d, const float* __restrict__ v_d,
               const float* __restrict__ W_out, const float* __restrict__ b_out,
               const float* __restrict__ y0,
               const unsigned* __restrict__ hpG, const float* __restrict__ hTG,
               float* __restrict__ out)
{
  const int tid = threadIdx.x;
  const int wid = tid >> 6;
  const int l   = tid & 63;
  const int b   = 2*blockIdx.x + wid;
  const int a    = l & 31;
  const int half = l >> 5;

  __shared__ __align__(16) unsigned char smem[18496];
  unsigned char* wbp = smem + wid*9248;
  unsigned* sh_hp   = (unsigned*)wbp;
  _Float16* sh_ring = (_Float16*)(wbp + 8704);
  float*    sh_hT   = (float*)(wbp + 8864);
  float*    sh_dp   = (float*)(wbp + 9120);

  {
    const uint4* src = (const uint4*)(hpG + (size_t)b * 2176);
    #pragma unroll
    for (int it = 0; it < 8; ++it)
      ((uint4*)sh_hp)[it*64 + l] = src[it*64 + l];
    const unsigned* s2 = hpG + (size_t)b*2176 + 2048;
    sh_hp[2048 + l] = s2[l];
    sh_hp[2112 + l] = s2[64 + l];
  }
  sh_hT[l] = hTG[(size_t)b*64 + l];

  unsigned wr_r[32], wr_z[32], wr_n[32];
  {
    const f4v* wp = (const f4v*)W_hh_d;
    #pragma unroll
    for (int k = 0; k < 16; ++k) {
      f4v vr = wp[l*16 + k];
      f4v vz = wp[(64 + l)*16 + k];
      f4v vn = wp[(128 + l)*16 + k];
      wr_r[2*k] = pk2(vr.x, vr.y); wr_r[2*k+1] = pk2(vr.z, vr.w);
      wr_z[2*k] = pk2(vz.x, vz.y); wr_z[2*k+1] = pk2(vz.z, vz.w);
      wr_n[2*k] = pk2(vn.x, vn.y); wr_n[2*k+1] = pk2(vn.z, vn.w);
    }
  }
  float wih0 = W_ih_d[l], wih1 = W_ih_d[64+l], wih2 = W_ih_d[128+l];
  float bb0  = b_ih_d[l] + b_hh_d[l];
  float bb1  = b_ih_d[64+l] + b_hh_d[64+l];
  float bih2 = b_ih_d[128+l], bhh2 = b_hh_d[128+l];
  unsigned udr[16];
  {
    const f2* up = (const f2*)(W_d + a*64 + half*32);
    #pragma unroll
    for (int k = 0; k < 16; ++k) { f2 f = up[k]; udr[k] = pk2(f.x, f.y); }
  }
  float dprev;
  {
    const f4v* wi = (const f4v*)(W_init + l*64);
    const f4v* hb = (const f4v*)sh_hT;
    f2 a0={0,0}, a1={0,0};
    #pragma unroll
    for (int k = 0; k < 16; ++k) {
      f4v wv = wi[k]; f4v hv = hb[k];
      a0 = pkfma(wv.xy, hv.xy, a0);
      a1 = pkfma(wv.zw, hv.zw, a1);
    }
    dprev = b_init[l] + (a0.x + a0.y) + (a1.x + a1.y);
  }
  float wout1 = W_out[l];
  float hw0 = __builtin_bit_cast(float, sh_hp[l*17 + 16]);
  float hw1 = __builtin_bit_cast(float, sh_hp[(64 + l)*17 + 16]);
  float oprev = y0[0];
  float bo = b_out[0];
  float c1;
  {
    float sv = v_d[a];
    sv += __shfl_xor(sv, 16); sv += __shfl_xor(sv, 8);
    sv += __shfl_xor(sv, 4);  sv += __shfl_xor(sv, 2); sv += __shfl_xor(sv, 1);
    c1 = LOG2E * sv;
  }
  sh_ring[l] = (_Float16)dprev;

  const unsigned* hpr0 = sh_hp + l*17;
  const unsigned* hpr1 = sh_hp + (64 + l)*17;

  #pragma unroll 1
  for (int s = 0; s < HOR; ++s) {
    float ar0=0,ar1=0,az0=0,az1=0,an0=0,an1=0;
    gru_mv(sh_ring, wr_r, wr_z, wr_n, ar0,ar1,az0,az1,an0,an1);
    float r = fsig(fmaf(oprev, wih0, bb0) + ar0 + ar1);
    float z = fsig(fmaf(oprev, wih1, bb1) + az0 + az1);
    float n = ftanh(fmaf(oprev, wih2, bih2) + r * (an0 + an1 + bhh2));
    float dnew = fmaf(z, dprev - n, n);
    dprev = dnew;
    sh_ring[l] = (_Float16)dnew;
    {
      float acc = proj_dot(sh_ring + half*32, udr);
      acc += __shfl_xor(acc, 32);
      if (l < 32) sh_dp[l] = C2 * acc;
    }
    float rs0 = 0.f, rs1 = 0.f;
    #pragma unroll
    for (int j2 = 0; j2 < 8; ++j2) {
      f4v dp = *(const f4v*)&sh_dp[4*j2];
      half2_t ha0 = bch(hpr0[2*j2]), hb0 = bch(hpr0[2*j2+1]);
      half2_t ha1 = bch(hpr1[2*j2]), hb1 = bch(hpr1[2*j2+1]);
      float v0 = v_d[4*j2], v1 = v_d[4*j2+1], v2 = v_d[4*j2+2], v3 = v_d[4*j2+3];
      rs0 = fmaf(v0, frcp(1.0f + fexp2(dp.x + (float)ha0.x)), rs0);
      rs0 = fmaf(v1, frcp(1.0f + fexp2(dp.y + (float)ha0.y)), rs0);
      rs0 = fmaf(v2, frcp(1.0f + fexp2(dp.z + (float)hb0.x)), rs0);
      rs0 = fmaf(v3, frcp(1.0f + fexp2(dp.w + (float)hb0.y)), rs0);
      rs1 = fmaf(v0, frcp(1.0f + fexp2(dp.x + (float)ha1.x)), rs1);
      rs1 = fmaf(v1, frcp(1.0f + fexp2(dp.y + (float)ha1.y)), rs1);
      rs1 = fmaf(v2, frcp(1.0f + fexp2(dp.z + (float)hb1.x)), rs1);
      rs1 = fmaf(v3, frcp(1.0f + fexp2(dp.w + (float)hb1.y)), rs1);
    }
    float e0 = fexp2(fmaf(-C2, rs0, c1));
    float e1 = fexp2(fmaf(-C2, rs1, c1));
    float P0 = rdl63(wavesum_dpp(e0 + e1));
    float P1 = rdl63(wavesum_dpp(fmaf(e0, hw0, e1 * hw1)));
    float P2 = rdl63(wavesum_dpp(wout1 * dnew));
    float o = fmaf(P1, frcp(P0), P2 + bo);
    if (l == 0) out[(size_t)b * HOR + s] = o;
    oprev = o;
  }
}

extern "C" void kernel_launch(void* const* d_in, const int* in_sizes, int n_in,
                              void* d_out, int out_size, void* d_ws, size_t ws_size,
                              hipStream_t stream) {
  const float* x      = (const float*)d_in[0];
  const float* W_ih_e = (const float*)d_in[1];
  const float* W_hh_e = (const float*)d_in[2];
  const float* b_ih_e = (const float*)d_in[3];
  const float* b_hh_e = (const float*)d_in[4];
  // d_in[5..8] = W_e, U_e, b_e, v_e : dead (softmax over size-1 axis == 1)
  const float* W_init = (const float*)d_in[9];
  const float* b_init = (const float*)d_in[10];
  const float* W_ih_d = (const float*)d_in[11];
  const float* W_hh_d = (const float*)d_in[12];
  const float* b_ih_d = (const float*)d_in[13];
  const float* b_hh_d = (const float*)d_in[14];
  const float* W_d    = (const float*)d_in[15];
  const float* U_d    = (const float*)d_in[16];
  const float* v_d    = (const float*)d_in[17];
  const float* W_out  = (const float*)d_in[18];
  const float* b_out  = (const float*)d_in[19];
  const float* y0     = (const float*)d_in[20];
  float* outp = (float*)d_out;

  unsigned* hpG = (unsigned*)d_ws;
  float*    hTG = (float*)((char*)d_ws + (size_t)BATCH * 2176 * 4);

  darnn_enc<<<BATCH/16, 256, 0, stream>>>(x, W_ih_e, W_hh_e, b_ih_e, b_hh_e,
      U_d, W_out, hpG, hTG);
  darnn_dec<<<BATCH/2, 128, 0, stream>>>(W_init, b_init, W_ih_d, W_hh_d,
      b_ih_d, b_hh_d, W_d, v_d, W_out, b_out, y0, hpG, hTG, outp);
}